// Round 2
// baseline (766.997 us; speedup 1.0000x reference)
//
#include <hip/hip_runtime.h>
#include <hip/hip_bf16.h>

// Problem dims (fixed by setup_inputs): L=2, B=32, S=2048, D=1024. All floats f32.
constexpr int LAY = 2;
constexpr int BB  = 32;
constexpr int SS  = 2048;
constexpr int DD  = 1024;

typedef unsigned short u16;
typedef short  short8  __attribute__((ext_vector_type(8)));
typedef u16    u16x8   __attribute__((ext_vector_type(8)));
typedef float  floatx4 __attribute__((ext_vector_type(4)));

__device__ inline u16 f2bf_rn(float f) {
    union { float f; unsigned int i; } v; v.f = f;
    unsigned int x = v.i;
    return (u16)((x + 0x7FFFu + ((x >> 16) & 1u)) >> 16);
}

// ---------------------------------------------------------------------------
// W_enc f32 [K][N] -> wT bf16 [N][K]
__global__ void transpose_wenc(const float* __restrict__ W, u16* __restrict__ wT) {
    int idx = blockIdx.x * 256 + threadIdx.x;   // 0 .. 1M-1
    int k = idx >> 10, n = idx & 1023;
    wT[n * DD + k] = f2bf_rn(W[idx]);
}

// ---------------------------------------------------------------------------
// dec_proj[b][f] = dec_hidden[L-1][b][:] @ W_dec[:, f] + b_dec[f]   (all f32)
__global__ __launch_bounds__(256) void dec_proj_kernel(
    const float* __restrict__ dec_hidden, const float* __restrict__ W_dec,
    const float* __restrict__ b_dec, float* __restrict__ dec_proj) {
    int b = blockIdx.x, t = threadIdx.x;
    const float* h = dec_hidden + (LAY - 1) * BB * DD + b * DD;
    float acc0 = 0.f, acc1 = 0.f, acc2 = 0.f, acc3 = 0.f;
    for (int e = 0; e < DD; ++e) {
        float hv = h[e];
        const float* wr = W_dec + e * DD;
        acc0 += hv * wr[t];
        acc1 += hv * wr[t + 256];
        acc2 += hv * wr[t + 512];
        acc3 += hv * wr[t + 768];
    }
    float* dp = dec_proj + b * DD;
    dp[t]       = acc0 + b_dec[t];
    dp[t + 256] = acc1 + b_dec[t + 256];
    dp[t + 512] = acc2 + b_dec[t + 512];
    dp[t + 768] = acc3 + b_dec[t + 768];
}

// ---------------------------------------------------------------------------
// Fused: E = enc @ W_enc;  scores[r] += sum_n tanh(E[r][n] + dec_proj[b][n] + b_enc[n]) * w_att[n]
// 128x128 tile, BK=64, 4 waves as 2x2 of 64x64, 16x16x32 bf16 MFMA.
// A (enc) is f32 in HBM -> converted to bf16 while staging into LDS.
constexpr int LDK = 72;   // 64 + 8 pad (keeps 16B row alignment, breaks pow2 banking)

__global__ __launch_bounds__(256) void score_gemm(
    const float* __restrict__ enc,    // [M][K] f32 row-major
    const u16*   __restrict__ wT,     // [N][K] bf16 row-major (W_enc transposed)
    const float* __restrict__ dec_proj,
    const float* __restrict__ b_enc, const float* __restrict__ w_att,
    float* __restrict__ scores) {
    __shared__ u16 As[128 * LDK];
    __shared__ u16 Bs[128 * LDK];

    const int tid  = threadIdx.x;
    const int bn   = blockIdx.x;           // 0..7
    const int bm   = blockIdx.y;           // 0..511
    const int row0 = bm * 128, col0 = bn * 128;
    const int lane = tid & 63, w = tid >> 6;
    const int wm   = w >> 1,  wn = w & 1;
    const int quad = lane >> 4, l16 = lane & 15;

    // staging: 128 rows x 64 k per tile; per-thread 4 chunks of 8 elems
    const int pr = tid >> 3;           // row 0..31 (i adds 32)
    const int pc = (tid & 7) * 8;      // k-offset within row (0..56)

    floatx4 acc[4][4];
    #pragma unroll
    for (int i = 0; i < 4; ++i)
        #pragma unroll
        for (int j = 0; j < 4; ++j)
            acc[i][j] = (floatx4){0.f, 0.f, 0.f, 0.f};

    for (int kt = 0; kt < DD / 64; ++kt) {
        const int k0 = kt * 64;
        floatx4 af0[4], af1[4];
        u16x8 bv[4];
        #pragma unroll
        for (int i = 0; i < 4; ++i) {
            int r = pr + i * 32;
            const float* src = enc + (size_t)(row0 + r) * DD + k0 + pc;
            af0[i] = *reinterpret_cast<const floatx4*>(src);
            af1[i] = *reinterpret_cast<const floatx4*>(src + 4);
            bv[i]  = *reinterpret_cast<const u16x8*>(&wT[(size_t)(col0 + r) * DD + k0 + pc]);
        }
        __syncthreads();
        #pragma unroll
        for (int i = 0; i < 4; ++i) {
            int r = pr + i * 32;
            u16x8 a8;
            #pragma unroll
            for (int j = 0; j < 4; ++j) {
                a8[j]     = f2bf_rn(af0[i][j]);
                a8[4 + j] = f2bf_rn(af1[i][j]);
            }
            *reinterpret_cast<u16x8*>(&As[r * LDK + pc]) = a8;
            *reinterpret_cast<u16x8*>(&Bs[r * LDK + pc]) = bv[i];
        }
        __syncthreads();
        #pragma unroll
        for (int ks = 0; ks < 2; ++ks) {
            short8 a[4], b[4];
            #pragma unroll
            for (int tm = 0; tm < 4; ++tm)
                a[tm] = *reinterpret_cast<const short8*>(
                    &As[(wm * 64 + tm * 16 + l16) * LDK + ks * 32 + quad * 8]);
            #pragma unroll
            for (int tn = 0; tn < 4; ++tn)
                b[tn] = *reinterpret_cast<const short8*>(
                    &Bs[(wn * 64 + tn * 16 + l16) * LDK + ks * 32 + quad * 8]);
            #pragma unroll
            for (int tm = 0; tm < 4; ++tm)
                #pragma unroll
                for (int tn = 0; tn < 4; ++tn)
                    acc[tm][tn] = __builtin_amdgcn_mfma_f32_16x16x32_bf16(
                        a[tm], b[tn], acc[tm][tn], 0, 0, 0);
        }
        __syncthreads();
    }

    // Epilogue: tanh + dot(w_att) + per-row reduce + atomicAdd
    // C/D layout (m89/m91-verified): col = lane&15, row = quad*4 + reg
    const int bIdx = row0 / SS;                 // one b per M-block (S % 128 == 0)
    const float* dp = dec_proj + bIdx * DD;
    float cvec[4], wvv[4];
    #pragma unroll
    for (int tn = 0; tn < 4; ++tn) {
        int n = col0 + wn * 64 + tn * 16 + l16;
        cvec[tn] = dp[n] + b_enc[n];
        wvv[tn]  = w_att[n];
    }
    #pragma unroll
    for (int tm = 0; tm < 4; ++tm) {
        float rs0 = 0.f, rs1 = 0.f, rs2 = 0.f, rs3 = 0.f;
        #pragma unroll
        for (int tn = 0; tn < 4; ++tn) {
            rs0 += tanhf(acc[tm][tn][0] + cvec[tn]) * wvv[tn];
            rs1 += tanhf(acc[tm][tn][1] + cvec[tn]) * wvv[tn];
            rs2 += tanhf(acc[tm][tn][2] + cvec[tn]) * wvv[tn];
            rs3 += tanhf(acc[tm][tn][3] + cvec[tn]) * wvv[tn];
        }
        #pragma unroll
        for (int off = 1; off < 16; off <<= 1) {
            rs0 += __shfl_xor(rs0, off, 64);
            rs1 += __shfl_xor(rs1, off, 64);
            rs2 += __shfl_xor(rs2, off, 64);
            rs3 += __shfl_xor(rs3, off, 64);
        }
        if (l16 == 0) {
            int rbase = row0 + wm * 64 + tm * 16 + quad * 4;
            atomicAdd(&scores[rbase + 0], rs0);
            atomicAdd(&scores[rbase + 1], rs1);
            atomicAdd(&scores[rbase + 2], rs2);
            atomicAdd(&scores[rbase + 3], rs3);
        }
    }
}

// ---------------------------------------------------------------------------
// Masked softmax over S per b. One block per b. b_att omitted (shift-invariant).
__global__ __launch_bounds__(256) void softmax_kernel(
    const float* __restrict__ scores, const int* __restrict__ mask,
    float* __restrict__ attn_out) {
    int b = blockIdx.x, t = threadIdx.x;
    const float* srow = scores + b * SS;
    const int*   mrow = mask + b * SS;
    float vals[8];
    float vmax = -1e30f;
    #pragma unroll
    for (int i = 0; i < 8; ++i) {
        int s = i * 256 + t;
        float v = (mrow[s] == 0) ? -1e10f : srow[s];
        vals[i] = v;
        vmax = fmaxf(vmax, v);
    }
    #pragma unroll
    for (int off = 32; off >= 1; off >>= 1) vmax = fmaxf(vmax, __shfl_xor(vmax, off, 64));
    __shared__ float sm[4];
    if ((t & 63) == 0) sm[t >> 6] = vmax;
    __syncthreads();
    vmax = fmaxf(fmaxf(sm[0], sm[1]), fmaxf(sm[2], sm[3]));
    float sum = 0.f;
    #pragma unroll
    for (int i = 0; i < 8; ++i) { vals[i] = __expf(vals[i] - vmax); sum += vals[i]; }
    #pragma unroll
    for (int off = 32; off >= 1; off >>= 1) sum += __shfl_xor(sum, off, 64);
    __shared__ float ssum[4];
    if ((t & 63) == 0) ssum[t >> 6] = sum;
    __syncthreads();
    sum = ssum[0] + ssum[1] + ssum[2] + ssum[3];
    float inv = 1.f / sum;
    #pragma unroll
    for (int i = 0; i < 8; ++i) {
        int s = i * 256 + t;
        attn_out[b * SS + s] = vals[i] * inv;
    }
}

// ---------------------------------------------------------------------------
// ctx[b][d] += sum_{s in chunk} attn[b][s] * enc[b][s][d]   (f32 atomic into d_out)
__global__ __launch_bounds__(256) void context_kernel(
    const float* __restrict__ attn, const float* __restrict__ enc,
    float* __restrict__ ctx) {
    int dcb = blockIdx.x;   // 0..3
    int scb = blockIdx.y;   // 0..7
    int b   = blockIdx.z;   // 0..31
    int d = dcb * 256 + threadIdx.x;
    const float* base = enc + ((size_t)b * SS + scb * 256) * DD + d;
    const float* ar   = attn + b * SS + scb * 256;
    float acc = 0.f;
    #pragma unroll 4
    for (int s = 0; s < 256; ++s) acc += ar[s] * base[(size_t)s * DD];
    atomicAdd(&ctx[b * DD + d], acc);
}

// ---------------------------------------------------------------------------
extern "C" void kernel_launch(void* const* d_in, const int* in_sizes, int n_in,
                              void* d_out, int out_size, void* d_ws, size_t ws_size,
                              hipStream_t stream) {
    const float* dec_hidden = (const float*)d_in[0];
    const float* enc        = (const float*)d_in[1];
    const int*   mask       = (const int*)d_in[2];
    const float* W_dec      = (const float*)d_in[3];
    const float* b_dec      = (const float*)d_in[4];
    const float* W_enc      = (const float*)d_in[5];
    const float* b_enc      = (const float*)d_in[6];
    const float* w_att      = (const float*)d_in[7];
    // d_in[8] (b_att): uniform shift into softmax -> no effect, omitted.

    float* out = (float*)d_out;               // [0,32768) context ; [32768,98304) attn
    float* ws  = (float*)d_ws;
    float* dec_proj = ws;                     // 32768 f32
    float* scores   = ws + 32768;             // 65536 f32
    u16*   wT       = (u16*)(ws + 98304);     // 1M bf16 (2 MB)
    float* attn     = out + 32768;            // attn written straight to d_out (f32)

    hipMemsetAsync(scores, 0, 65536 * sizeof(float), stream);
    hipMemsetAsync(out, 0, 32768 * sizeof(float), stream);   // context accumulator

    transpose_wenc<<<4096, 256, 0, stream>>>(W_enc, wT);
    dec_proj_kernel<<<32, 256, 0, stream>>>(dec_hidden, W_dec, b_dec, dec_proj);
    score_gemm<<<dim3(8, 512), 256, 0, stream>>>(enc, wT, dec_proj, b_enc, w_att, scores);
    softmax_kernel<<<32, 256, 0, stream>>>(scores, mask, attn);
    context_kernel<<<dim3(4, 8, 32), 256, 0, stream>>>(attn, enc, out);
}

// Round 3
// 715.556 us; speedup vs baseline: 1.0719x; 1.0719x over previous
//
#include <hip/hip_runtime.h>
#include <hip/hip_bf16.h>

// Problem dims (fixed by setup_inputs): L=2, B=32, S=2048, D=1024. All floats f32.
constexpr int LAY = 2;
constexpr int BB  = 32;
constexpr int SS  = 2048;
constexpr int DD  = 1024;

typedef unsigned short u16;
typedef short  short8  __attribute__((ext_vector_type(8)));
typedef u16    u16x8   __attribute__((ext_vector_type(8)));
typedef u16    u16x4   __attribute__((ext_vector_type(4)));
typedef float  floatx4 __attribute__((ext_vector_type(4)));

__device__ inline float bf2f(u16 u) {
    union { unsigned int i; float f; } v; v.i = ((unsigned int)u) << 16; return v.f;
}
__device__ inline u16 f2bf_rn(float f) {
    union { float f; unsigned int i; } v; v.f = f;
    unsigned int x = v.i;
    return (u16)((x + 0x7FFFu + ((x >> 16) & 1u)) >> 16);
}

__device__ __forceinline__ void gload_lds16(const u16* g, u16* l) {
    __builtin_amdgcn_global_load_lds(
        (const __attribute__((address_space(1))) void*)g,
        (__attribute__((address_space(3))) void*)l, 16, 0, 0);
}

// ---------------------------------------------------------------------------
// enc f32 -> bf16 (rn). 4 elems/thread.
__global__ __launch_bounds__(256) void convert_enc(const float* __restrict__ enc,
                                                   u16* __restrict__ encbf) {
    size_t i = ((size_t)blockIdx.x * 256 + threadIdx.x) * 4;
    floatx4 v = *reinterpret_cast<const floatx4*>(enc + i);
    u16x4 r;
    #pragma unroll
    for (int j = 0; j < 4; ++j) r[j] = f2bf_rn(v[j]);
    *reinterpret_cast<u16x4*>(encbf + i) = r;
}

// W_enc f32 [K][N] -> wT bf16 [N][K]
__global__ void transpose_wenc(const float* __restrict__ W, u16* __restrict__ wT) {
    int idx = blockIdx.x * 256 + threadIdx.x;   // 0 .. 1M-1
    int k = idx >> 10, n = idx & 1023;
    wT[n * DD + k] = f2bf_rn(W[idx]);
}

// ---------------------------------------------------------------------------
// dec_proj[b][col] = dec_hidden[L-1][b][:] @ W_dec[:, col] + b_dec[col]   (f32)
__global__ __launch_bounds__(256) void dec_proj_kernel(
    const float* __restrict__ dec_hidden, const float* __restrict__ W_dec,
    const float* __restrict__ b_dec, float* __restrict__ dec_proj) {
    int cb = blockIdx.x, b = blockIdx.y, t = threadIdx.x;
    int col = cb * 256 + t;
    const float* h = dec_hidden + (LAY - 1) * BB * DD + b * DD;
    float a0 = 0.f, a1 = 0.f, a2 = 0.f, a3 = 0.f;
    for (int e = 0; e < DD; e += 4) {
        a0 += h[e + 0] * W_dec[(size_t)(e + 0) * DD + col];
        a1 += h[e + 1] * W_dec[(size_t)(e + 1) * DD + col];
        a2 += h[e + 2] * W_dec[(size_t)(e + 2) * DD + col];
        a3 += h[e + 3] * W_dec[(size_t)(e + 3) * DD + col];
    }
    dec_proj[b * DD + col] = (a0 + a1) + (a2 + a3) + b_dec[col];
}

// ---------------------------------------------------------------------------
// Fused: E = enc @ W_enc;  scores[r] += sum_n tanh(E[r][n] + dec_proj[b][n] + b_enc[n]) * w_att[n]
// bf16 path: 128x128 tile, BK=64, global_load_lds width-16 staging (m97-style,
// unpadded LDS: contiguity required by the wave-uniform-base + lane*16 DMA).
__global__ __launch_bounds__(256) void score_gemm_bf(
    const u16* __restrict__ enc,      // [M][K] bf16 row-major
    const u16* __restrict__ wT,       // [N][K] bf16 row-major
    const float* __restrict__ dec_proj,
    const float* __restrict__ b_enc, const float* __restrict__ w_att,
    float* __restrict__ scores) {
    __shared__ u16 As[128 * 64];
    __shared__ u16 Bs[128 * 64];

    const int tid  = threadIdx.x;
    const int bn   = blockIdx.x;           // 0..7
    const int bm   = blockIdx.y;           // 0..511
    const int row0 = bm * 128, col0 = bn * 128;
    const int lane = tid & 63, w = tid >> 6;
    const int wm   = w >> 1,  wn = w & 1;
    const int quad = lane >> 4, l16 = lane & 15;

    // staging: wave w, issue i covers rows [i*32 + w*8, +8); lane -> (row, kchunk)
    const int srow = w * 8 + (lane >> 3);
    const int scol = (lane & 7) * 8;

    floatx4 acc[4][4];
    #pragma unroll
    for (int i = 0; i < 4; ++i)
        #pragma unroll
        for (int j = 0; j < 4; ++j)
            acc[i][j] = (floatx4){0.f, 0.f, 0.f, 0.f};

    for (int kt = 0; kt < DD / 64; ++kt) {
        const int k0 = kt * 64;
        __syncthreads();   // prev MFMA reads done before LDS overwrite
        #pragma unroll
        for (int i = 0; i < 4; ++i) {
            gload_lds16(&enc[(size_t)(row0 + i * 32 + srow) * DD + k0 + scol],
                        &As[(i * 32 + w * 8) * 64]);
            gload_lds16(&wT [(size_t)(col0 + i * 32 + srow) * DD + k0 + scol],
                        &Bs[(i * 32 + w * 8) * 64]);
        }
        __syncthreads();   // drains vmcnt (DMA complete) + barrier
        #pragma unroll
        for (int ks = 0; ks < 2; ++ks) {
            short8 a[4], b[4];
            #pragma unroll
            for (int tm = 0; tm < 4; ++tm)
                a[tm] = *reinterpret_cast<const short8*>(
                    &As[(wm * 64 + tm * 16 + l16) * 64 + ks * 32 + quad * 8]);
            #pragma unroll
            for (int tn = 0; tn < 4; ++tn)
                b[tn] = *reinterpret_cast<const short8*>(
                    &Bs[(wn * 64 + tn * 16 + l16) * 64 + ks * 32 + quad * 8]);
            #pragma unroll
            for (int tm = 0; tm < 4; ++tm)
                #pragma unroll
                for (int tn = 0; tn < 4; ++tn)
                    acc[tm][tn] = __builtin_amdgcn_mfma_f32_16x16x32_bf16(
                        a[tm], b[tn], acc[tm][tn], 0, 0, 0);
        }
    }

    // Epilogue: tanh + dot(w_att) + per-row reduce + atomicAdd
    // C/D layout (m89/m91-verified): col = lane&15, row = quad*4 + reg
    const int bIdx = row0 / SS;
    const float* dp = dec_proj + bIdx * DD;
    float cvec[4], wvv[4];
    #pragma unroll
    for (int tn = 0; tn < 4; ++tn) {
        int n = col0 + wn * 64 + tn * 16 + l16;
        cvec[tn] = dp[n] + b_enc[n];
        wvv[tn]  = w_att[n];
    }
    #pragma unroll
    for (int tm = 0; tm < 4; ++tm) {
        float rs0 = 0.f, rs1 = 0.f, rs2 = 0.f, rs3 = 0.f;
        #pragma unroll
        for (int tn = 0; tn < 4; ++tn) {
            rs0 += tanhf(acc[tm][tn][0] + cvec[tn]) * wvv[tn];
            rs1 += tanhf(acc[tm][tn][1] + cvec[tn]) * wvv[tn];
            rs2 += tanhf(acc[tm][tn][2] + cvec[tn]) * wvv[tn];
            rs3 += tanhf(acc[tm][tn][3] + cvec[tn]) * wvv[tn];
        }
        #pragma unroll
        for (int off = 1; off < 16; off <<= 1) {
            rs0 += __shfl_xor(rs0, off, 64);
            rs1 += __shfl_xor(rs1, off, 64);
            rs2 += __shfl_xor(rs2, off, 64);
            rs3 += __shfl_xor(rs3, off, 64);
        }
        if (l16 == 0) {
            int rbase = row0 + wm * 64 + tm * 16 + quad * 4;
            atomicAdd(&scores[rbase + 0], rs0);
            atomicAdd(&scores[rbase + 1], rs1);
            atomicAdd(&scores[rbase + 2], rs2);
            atomicAdd(&scores[rbase + 3], rs3);
        }
    }
}

// ---- f32-A fallback path (round-2 staging), used only if ws too small ------
constexpr int LDK2 = 72;
__global__ __launch_bounds__(256) void score_gemm_f32(
    const float* __restrict__ enc, const u16* __restrict__ wT,
    const float* __restrict__ dec_proj,
    const float* __restrict__ b_enc, const float* __restrict__ w_att,
    float* __restrict__ scores) {
    __shared__ u16 As[128 * LDK2];
    __shared__ u16 Bs[128 * LDK2];
    const int tid  = threadIdx.x;
    const int bn   = blockIdx.x, bm = blockIdx.y;
    const int row0 = bm * 128, col0 = bn * 128;
    const int lane = tid & 63, w = tid >> 6;
    const int wm   = w >> 1,  wn = w & 1;
    const int quad = lane >> 4, l16 = lane & 15;
    const int pr = tid >> 3, pc = (tid & 7) * 8;

    floatx4 acc[4][4];
    #pragma unroll
    for (int i = 0; i < 4; ++i)
        #pragma unroll
        for (int j = 0; j < 4; ++j) acc[i][j] = (floatx4){0.f, 0.f, 0.f, 0.f};

    for (int kt = 0; kt < DD / 64; ++kt) {
        const int k0 = kt * 64;
        floatx4 af0[4], af1[4];
        u16x8 bv[4];
        #pragma unroll
        for (int i = 0; i < 4; ++i) {
            int r = pr + i * 32;
            const float* src = enc + (size_t)(row0 + r) * DD + k0 + pc;
            af0[i] = *reinterpret_cast<const floatx4*>(src);
            af1[i] = *reinterpret_cast<const floatx4*>(src + 4);
            bv[i]  = *reinterpret_cast<const u16x8*>(&wT[(size_t)(col0 + r) * DD + k0 + pc]);
        }
        __syncthreads();
        #pragma unroll
        for (int i = 0; i < 4; ++i) {
            int r = pr + i * 32;
            u16x8 a8;
            #pragma unroll
            for (int j = 0; j < 4; ++j) { a8[j] = f2bf_rn(af0[i][j]); a8[4 + j] = f2bf_rn(af1[i][j]); }
            *reinterpret_cast<u16x8*>(&As[r * LDK2 + pc]) = a8;
            *reinterpret_cast<u16x8*>(&Bs[r * LDK2 + pc]) = bv[i];
        }
        __syncthreads();
        #pragma unroll
        for (int ks = 0; ks < 2; ++ks) {
            short8 a[4], b[4];
            #pragma unroll
            for (int tm = 0; tm < 4; ++tm)
                a[tm] = *reinterpret_cast<const short8*>(
                    &As[(wm * 64 + tm * 16 + l16) * LDK2 + ks * 32 + quad * 8]);
            #pragma unroll
            for (int tn = 0; tn < 4; ++tn)
                b[tn] = *reinterpret_cast<const short8*>(
                    &Bs[(wn * 64 + tn * 16 + l16) * LDK2 + ks * 32 + quad * 8]);
            #pragma unroll
            for (int tm = 0; tm < 4; ++tm)
                #pragma unroll
                for (int tn = 0; tn < 4; ++tn)
                    acc[tm][tn] = __builtin_amdgcn_mfma_f32_16x16x32_bf16(
                        a[tm], b[tn], acc[tm][tn], 0, 0, 0);
        }
        __syncthreads();
    }
    const int bIdx = row0 / SS;
    const float* dp = dec_proj + bIdx * DD;
    float cvec[4], wvv[4];
    #pragma unroll
    for (int tn = 0; tn < 4; ++tn) {
        int n = col0 + wn * 64 + tn * 16 + l16;
        cvec[tn] = dp[n] + b_enc[n];
        wvv[tn]  = w_att[n];
    }
    #pragma unroll
    for (int tm = 0; tm < 4; ++tm) {
        float rs0 = 0.f, rs1 = 0.f, rs2 = 0.f, rs3 = 0.f;
        #pragma unroll
        for (int tn = 0; tn < 4; ++tn) {
            rs0 += tanhf(acc[tm][tn][0] + cvec[tn]) * wvv[tn];
            rs1 += tanhf(acc[tm][tn][1] + cvec[tn]) * wvv[tn];
            rs2 += tanhf(acc[tm][tn][2] + cvec[tn]) * wvv[tn];
            rs3 += tanhf(acc[tm][tn][3] + cvec[tn]) * wvv[tn];
        }
        #pragma unroll
        for (int off = 1; off < 16; off <<= 1) {
            rs0 += __shfl_xor(rs0, off, 64);
            rs1 += __shfl_xor(rs1, off, 64);
            rs2 += __shfl_xor(rs2, off, 64);
            rs3 += __shfl_xor(rs3, off, 64);
        }
        if (l16 == 0) {
            int rbase = row0 + wm * 64 + tm * 16 + quad * 4;
            atomicAdd(&scores[rbase + 0], rs0);
            atomicAdd(&scores[rbase + 1], rs1);
            atomicAdd(&scores[rbase + 2], rs2);
            atomicAdd(&scores[rbase + 3], rs3);
        }
    }
}

// ---------------------------------------------------------------------------
// Masked softmax over S per b. b_att omitted (shift-invariant).
__global__ __launch_bounds__(256) void softmax_kernel(
    const float* __restrict__ scores, const int* __restrict__ mask,
    float* __restrict__ attn_out) {
    int b = blockIdx.x, t = threadIdx.x;
    const float* srow = scores + b * SS;
    const int*   mrow = mask + b * SS;
    float vals[8];
    float vmax = -1e30f;
    #pragma unroll
    for (int i = 0; i < 8; ++i) {
        int s = i * 256 + t;
        float v = (mrow[s] == 0) ? -1e10f : srow[s];
        vals[i] = v;
        vmax = fmaxf(vmax, v);
    }
    #pragma unroll
    for (int off = 32; off >= 1; off >>= 1) vmax = fmaxf(vmax, __shfl_xor(vmax, off, 64));
    __shared__ float sm[4];
    if ((t & 63) == 0) sm[t >> 6] = vmax;
    __syncthreads();
    vmax = fmaxf(fmaxf(sm[0], sm[1]), fmaxf(sm[2], sm[3]));
    float sum = 0.f;
    #pragma unroll
    for (int i = 0; i < 8; ++i) { vals[i] = __expf(vals[i] - vmax); sum += vals[i]; }
    #pragma unroll
    for (int off = 32; off >= 1; off >>= 1) sum += __shfl_xor(sum, off, 64);
    __shared__ float ssum[4];
    if ((t & 63) == 0) ssum[t >> 6] = sum;
    __syncthreads();
    sum = ssum[0] + ssum[1] + ssum[2] + ssum[3];
    float inv = 1.f / sum;
    #pragma unroll
    for (int i = 0; i < 8; ++i) attn_out[b * SS + i * 256 + t] = vals[i] * inv;
}

// ---------------------------------------------------------------------------
// ctx[b][d..d+3] += sum_s attn[b][s] * encbf[b][s][d..d+3]
__global__ __launch_bounds__(256) void context_bf(
    const float* __restrict__ attn, const u16* __restrict__ encbf,
    float* __restrict__ ctx) {
    int scb = blockIdx.x;   // 0..7
    int b   = blockIdx.y;   // 0..31
    int d = threadIdx.x * 4;
    const u16*  base = encbf + ((size_t)b * SS + scb * 256) * DD + d;
    const float* ar  = attn + b * SS + scb * 256;
    float a0 = 0.f, a1 = 0.f, a2 = 0.f, a3 = 0.f;
    #pragma unroll 4
    for (int s = 0; s < 256; ++s) {
        u16x4 v = *reinterpret_cast<const u16x4*>(base + (size_t)s * DD);
        float w = ar[s];
        a0 += w * bf2f(v[0]); a1 += w * bf2f(v[1]);
        a2 += w * bf2f(v[2]); a3 += w * bf2f(v[3]);
    }
    atomicAdd(&ctx[b * DD + d + 0], a0);
    atomicAdd(&ctx[b * DD + d + 1], a1);
    atomicAdd(&ctx[b * DD + d + 2], a2);
    atomicAdd(&ctx[b * DD + d + 3], a3);
}

__global__ __launch_bounds__(256) void context_f32(
    const float* __restrict__ attn, const float* __restrict__ enc,
    float* __restrict__ ctx) {
    int dcb = blockIdx.x, scb = blockIdx.y, b = blockIdx.z;
    int d = dcb * 256 + threadIdx.x;
    const float* base = enc + ((size_t)b * SS + scb * 256) * DD + d;
    const float* ar   = attn + b * SS + scb * 256;
    float acc = 0.f;
    #pragma unroll 4
    for (int s = 0; s < 256; ++s) acc += ar[s] * base[(size_t)s * DD];
    atomicAdd(&ctx[b * DD + d], acc);
}

// ---------------------------------------------------------------------------
extern "C" void kernel_launch(void* const* d_in, const int* in_sizes, int n_in,
                              void* d_out, int out_size, void* d_ws, size_t ws_size,
                              hipStream_t stream) {
    const float* dec_hidden = (const float*)d_in[0];
    const float* enc        = (const float*)d_in[1];
    const int*   mask       = (const int*)d_in[2];
    const float* W_dec      = (const float*)d_in[3];
    const float* b_dec      = (const float*)d_in[4];
    const float* W_enc      = (const float*)d_in[5];
    const float* b_enc      = (const float*)d_in[6];
    const float* w_att      = (const float*)d_in[7];
    // d_in[8] (b_att): uniform shift into softmax -> no effect, omitted.

    float* out = (float*)d_out;               // [0,32768) context ; [32768,98304) attn
    float* ws  = (float*)d_ws;
    float* dec_proj = ws;                     // 32768 f32
    float* scores   = ws + 32768;             // 65536 f32
    u16*   wT       = (u16*)(ws + 98304);     // 1M bf16 (2 MB)
    u16*   encbf    = (u16*)(ws + 622592);    // 64M bf16 (128 MB)
    float* attn     = out + 32768;

    const size_t need = (size_t)622592 * 4 + (size_t)BB * SS * DD * 2;
    const bool use_bf = ws_size >= need;

    hipMemsetAsync(scores, 0, 65536 * sizeof(float), stream);
    hipMemsetAsync(out, 0, 32768 * sizeof(float), stream);   // context accumulator

    transpose_wenc<<<4096, 256, 0, stream>>>(W_enc, wT);
    dec_proj_kernel<<<dim3(4, 32), 256, 0, stream>>>(dec_hidden, W_dec, b_dec, dec_proj);
    if (use_bf) {
        convert_enc<<<65536, 256, 0, stream>>>(enc, encbf);
        score_gemm_bf<<<dim3(8, 512), 256, 0, stream>>>(encbf, wT, dec_proj, b_enc, w_att, scores);
        softmax_kernel<<<32, 256, 0, stream>>>(scores, mask, attn);
        context_bf<<<dim3(8, 32), 256, 0, stream>>>(attn, encbf, out);
    } else {
        score_gemm_f32<<<dim3(8, 512), 256, 0, stream>>>(enc, wT, dec_proj, b_enc, w_att, scores);
        softmax_kernel<<<32, 256, 0, stream>>>(scores, mask, attn);
        context_f32<<<dim3(4, 8, 32), 256, 0, stream>>>(attn, enc, out);
    }
}

// Round 4
// 696.096 us; speedup vs baseline: 1.1019x; 1.0280x over previous
//
#include <hip/hip_runtime.h>
#include <hip/hip_bf16.h>

// Problem dims (fixed by setup_inputs): L=2, B=32, S=2048, D=1024. All floats f32.
constexpr int LAY = 2;
constexpr int BB  = 32;
constexpr int SS  = 2048;
constexpr int DD  = 1024;

typedef unsigned short u16;
typedef short  short8  __attribute__((ext_vector_type(8)));
typedef u16    u16x8   __attribute__((ext_vector_type(8)));
typedef float  floatx4 __attribute__((ext_vector_type(4)));

__device__ inline float bf2f(u16 u) {
    union { unsigned int i; float f; } v; v.i = ((unsigned int)u) << 16; return v.f;
}
__device__ inline u16 f2bf_rn(float f) {
    union { float f; unsigned int i; } v; v.f = f;
    unsigned int x = v.i;
    return (u16)((x + 0x7FFFu + ((x >> 16) & 1u)) >> 16);
}

__device__ __forceinline__ void gload_lds16(const u16* g, u16* l) {
    __builtin_amdgcn_global_load_lds(
        (const __attribute__((address_space(1))) void*)g,
        (__attribute__((address_space(3))) void*)l, 16, 0, 0);
}

// ---------------------------------------------------------------------------
// enc f32 -> bf16 (rn). Grid-stride: 2048 blocks x 256 thr x 16 iters x 8 elems.
__global__ __launch_bounds__(256) void convert_enc(const float* __restrict__ enc,
                                                   u16* __restrict__ encbf) {
    size_t gid = (size_t)blockIdx.x * 256 + threadIdx.x;   // 0..524287
    #pragma unroll 4
    for (int it = 0; it < 16; ++it) {
        size_t i = (it * 524288ull + gid) * 8;
        floatx4 v0 = *reinterpret_cast<const floatx4*>(enc + i);
        floatx4 v1 = *reinterpret_cast<const floatx4*>(enc + i + 4);
        u16x8 r;
        #pragma unroll
        for (int j = 0; j < 4; ++j) { r[j] = f2bf_rn(v0[j]); r[4 + j] = f2bf_rn(v1[j]); }
        *reinterpret_cast<u16x8*>(encbf + i) = r;
    }
}

// W_enc f32 [K][N] -> wT bf16 [N][K]. Thread handles (n, 8 consecutive k).
// gid = c*1024 + n so consecutive threads share c -> coalesced reads over n.
__global__ __launch_bounds__(256) void transpose_wenc(const float* __restrict__ W,
                                                      u16* __restrict__ wT) {
    int gid = blockIdx.x * 256 + threadIdx.x;   // 0..131071
    int n = gid & 1023, c = gid >> 10;          // c: 0..127
    int k0 = c * 8;
    u16x8 r;
    #pragma unroll
    for (int j = 0; j < 8; ++j) r[j] = f2bf_rn(W[(size_t)(k0 + j) * DD + n]);
    *reinterpret_cast<u16x8*>(&wT[(size_t)n * DD + k0]) = r;
}

// ---------------------------------------------------------------------------
// dec_proj[b][col] += sum_{e in kc-chunk} h[e] * W_dec[e][col]  (+b_dec on kc==0)
// 4-way K-split for latency; dec_proj must be zeroed first.
__global__ __launch_bounds__(256) void dec_proj_kernel(
    const float* __restrict__ dec_hidden, const float* __restrict__ W_dec,
    const float* __restrict__ b_dec, float* __restrict__ dec_proj) {
    int kc = blockIdx.x, cb = blockIdx.y, b = blockIdx.z, t = threadIdx.x;
    int col = cb * 256 + t;
    const float* h = dec_hidden + (LAY - 1) * BB * DD + b * DD + kc * 256;
    const float* Wp = W_dec + (size_t)kc * 256 * DD + col;
    float a0 = 0.f, a1 = 0.f, a2 = 0.f, a3 = 0.f;
    for (int e = 0; e < 256; e += 4) {
        a0 += h[e + 0] * Wp[(size_t)(e + 0) * DD];
        a1 += h[e + 1] * Wp[(size_t)(e + 1) * DD];
        a2 += h[e + 2] * Wp[(size_t)(e + 2) * DD];
        a3 += h[e + 3] * Wp[(size_t)(e + 3) * DD];
    }
    float v = (a0 + a1) + (a2 + a3);
    if (kc == 0) v += b_dec[col];
    atomicAdd(&dec_proj[b * DD + col], v);
}

// ---------------------------------------------------------------------------
// Fused: E = enc @ W_enc;  scores[r] += sum_n tanh(E[r][n] + dec_proj[b][n] + b_enc[n]) * w_att[n]
// 128x128 tile, BK=64, global_load_lds width-16 staging with XOR-swizzled LDS:
// LDS 16B-chunk (row, kcs) holds global kchunk kc = kcs ^ (row&7). The DMA
// destination (wave-uniform base + lane*16) is fixed; the swizzle is applied
// to the per-lane SOURCE address. Kills the 16-way ds_read_b128 conflicts.
__global__ __launch_bounds__(256) void score_gemm_bf(
    const u16* __restrict__ enc,      // [M][K] bf16 row-major
    const u16* __restrict__ wT,       // [N][K] bf16 row-major
    const float* __restrict__ dec_proj,
    const float* __restrict__ b_enc, const float* __restrict__ w_att,
    float* __restrict__ scores) {
    __shared__ u16 As[128 * 64];
    __shared__ u16 Bs[128 * 64];

    const int tid  = threadIdx.x;
    const int bn   = blockIdx.x;           // 0..7
    const int bm   = blockIdx.y;           // 0..511
    const int row0 = bm * 128, col0 = bn * 128;
    const int lane = tid & 63, w = tid >> 6;
    const int wm   = w >> 1,  wn = w & 1;
    const int quad = lane >> 4, l16 = lane & 15;

    // staging: wave w, issue i covers rows [i*32 + w*8, +8)
    // lane l -> local row l>>3, LDS kchunk slot l&7, global kchunk (l&7)^(l>>3)
    const int srow = w * 8 + (lane >> 3);
    const int scol = (((lane & 7) ^ (lane >> 3)) * 8);

    floatx4 acc[4][4];
    #pragma unroll
    for (int i = 0; i < 4; ++i)
        #pragma unroll
        for (int j = 0; j < 4; ++j)
            acc[i][j] = (floatx4){0.f, 0.f, 0.f, 0.f};

    for (int kt = 0; kt < DD / 64; ++kt) {
        const int k0 = kt * 64;
        __syncthreads();   // prev MFMA reads done before LDS overwrite
        #pragma unroll
        for (int i = 0; i < 4; ++i) {
            gload_lds16(&enc[(size_t)(row0 + i * 32 + srow) * DD + k0 + scol],
                        &As[(i * 32 + w * 8) * 64]);
            gload_lds16(&wT [(size_t)(col0 + i * 32 + srow) * DD + k0 + scol],
                        &Bs[(i * 32 + w * 8) * 64]);
        }
        __syncthreads();   // drains vmcnt (DMA complete) + barrier
        #pragma unroll
        for (int ks = 0; ks < 2; ++ks) {
            short8 a[4], b[4];
            #pragma unroll
            for (int tm = 0; tm < 4; ++tm) {
                int r = wm * 64 + tm * 16 + l16;
                int kcs = (ks * 4 + quad) ^ (l16 & 7);
                a[tm] = *reinterpret_cast<const short8*>(&As[r * 64 + kcs * 8]);
            }
            #pragma unroll
            for (int tn = 0; tn < 4; ++tn) {
                int r = wn * 64 + tn * 16 + l16;
                int kcs = (ks * 4 + quad) ^ (l16 & 7);
                b[tn] = *reinterpret_cast<const short8*>(&Bs[r * 64 + kcs * 8]);
            }
            #pragma unroll
            for (int tm = 0; tm < 4; ++tm)
                #pragma unroll
                for (int tn = 0; tn < 4; ++tn)
                    acc[tm][tn] = __builtin_amdgcn_mfma_f32_16x16x32_bf16(
                        a[tm], b[tn], acc[tm][tn], 0, 0, 0);
        }
    }

    // Epilogue: tanh + dot(w_att) + per-row reduce + atomicAdd
    // C/D layout (m89/m91-verified): col = lane&15, row = quad*4 + reg
    const int bIdx = row0 / SS;
    const float* dp = dec_proj + bIdx * DD;
    float cvec[4], wvv[4];
    #pragma unroll
    for (int tn = 0; tn < 4; ++tn) {
        int n = col0 + wn * 64 + tn * 16 + l16;
        cvec[tn] = dp[n] + b_enc[n];
        wvv[tn]  = w_att[n];
    }
    #pragma unroll
    for (int tm = 0; tm < 4; ++tm) {
        float rs0 = 0.f, rs1 = 0.f, rs2 = 0.f, rs3 = 0.f;
        #pragma unroll
        for (int tn = 0; tn < 4; ++tn) {
            rs0 += tanhf(acc[tm][tn][0] + cvec[tn]) * wvv[tn];
            rs1 += tanhf(acc[tm][tn][1] + cvec[tn]) * wvv[tn];
            rs2 += tanhf(acc[tm][tn][2] + cvec[tn]) * wvv[tn];
            rs3 += tanhf(acc[tm][tn][3] + cvec[tn]) * wvv[tn];
        }
        #pragma unroll
        for (int off = 1; off < 16; off <<= 1) {
            rs0 += __shfl_xor(rs0, off, 64);
            rs1 += __shfl_xor(rs1, off, 64);
            rs2 += __shfl_xor(rs2, off, 64);
            rs3 += __shfl_xor(rs3, off, 64);
        }
        if (l16 == 0) {
            int rbase = row0 + wm * 64 + tm * 16 + quad * 4;
            atomicAdd(&scores[rbase + 0], rs0);
            atomicAdd(&scores[rbase + 1], rs1);
            atomicAdd(&scores[rbase + 2], rs2);
            atomicAdd(&scores[rbase + 3], rs3);
        }
    }
}

// ---------------------------------------------------------------------------
// Masked softmax over S per b. b_att omitted (shift-invariant).
__global__ __launch_bounds__(256) void softmax_kernel(
    const float* __restrict__ scores, const int* __restrict__ mask,
    float* __restrict__ attn_out) {
    int b = blockIdx.x, t = threadIdx.x;
    const float* srow = scores + b * SS;
    const int*   mrow = mask + b * SS;
    float vals[8];
    float vmax = -1e30f;
    #pragma unroll
    for (int i = 0; i < 8; ++i) {
        int s = i * 256 + t;
        float v = (mrow[s] == 0) ? -1e10f : srow[s];
        vals[i] = v;
        vmax = fmaxf(vmax, v);
    }
    #pragma unroll
    for (int off = 32; off >= 1; off >>= 1) vmax = fmaxf(vmax, __shfl_xor(vmax, off, 64));
    __shared__ float sm[4];
    if ((t & 63) == 0) sm[t >> 6] = vmax;
    __syncthreads();
    vmax = fmaxf(fmaxf(sm[0], sm[1]), fmaxf(sm[2], sm[3]));
    float sum = 0.f;
    #pragma unroll
    for (int i = 0; i < 8; ++i) { vals[i] = __expf(vals[i] - vmax); sum += vals[i]; }
    #pragma unroll
    for (int off = 32; off >= 1; off >>= 1) sum += __shfl_xor(sum, off, 64);
    __shared__ float ssum[4];
    if ((t & 63) == 0) ssum[t >> 6] = sum;
    __syncthreads();
    sum = ssum[0] + ssum[1] + ssum[2] + ssum[3];
    float inv = 1.f / sum;
    #pragma unroll
    for (int i = 0; i < 8; ++i) attn_out[b * SS + i * 256 + t] = vals[i] * inv;
}

// ---------------------------------------------------------------------------
// ctx[b][d..d+3] += sum_s attn[b][s] * encbf[b][s][d..d+3]
__global__ __launch_bounds__(256) void context_bf(
    const float* __restrict__ attn, const u16* __restrict__ encbf,
    float* __restrict__ ctx) {
    int scb = blockIdx.x;   // 0..7
    int b   = blockIdx.y;   // 0..31
    int d = threadIdx.x * 4;
    const u16*  base = encbf + ((size_t)b * SS + scb * 256) * DD + d;
    const float* ar  = attn + b * SS + scb * 256;
    float a0 = 0.f, a1 = 0.f, a2 = 0.f, a3 = 0.f;
    #pragma unroll 4
    for (int s = 0; s < 256; ++s) {
        u16x8 dummy; (void)dummy;
        unsigned long long v = *reinterpret_cast<const unsigned long long*>(base + (size_t)s * DD);
        float w = ar[s];
        a0 += w * bf2f((u16)(v       & 0xFFFF));
        a1 += w * bf2f((u16)((v >> 16) & 0xFFFF));
        a2 += w * bf2f((u16)((v >> 32) & 0xFFFF));
        a3 += w * bf2f((u16)((v >> 48) & 0xFFFF));
    }
    atomicAdd(&ctx[b * DD + d + 0], a0);
    atomicAdd(&ctx[b * DD + d + 1], a1);
    atomicAdd(&ctx[b * DD + d + 2], a2);
    atomicAdd(&ctx[b * DD + d + 3], a3);
}

// ---------------------------------------------------------------------------
extern "C" void kernel_launch(void* const* d_in, const int* in_sizes, int n_in,
                              void* d_out, int out_size, void* d_ws, size_t ws_size,
                              hipStream_t stream) {
    const float* dec_hidden = (const float*)d_in[0];
    const float* enc        = (const float*)d_in[1];
    const int*   mask       = (const int*)d_in[2];
    const float* W_dec      = (const float*)d_in[3];
    const float* b_dec      = (const float*)d_in[4];
    const float* W_enc      = (const float*)d_in[5];
    const float* b_enc      = (const float*)d_in[6];
    const float* w_att      = (const float*)d_in[7];
    // d_in[8] (b_att): uniform shift into softmax -> no effect, omitted.

    float* out = (float*)d_out;               // [0,32768) context ; [32768,98304) attn
    float* ws  = (float*)d_ws;
    float* dec_proj = ws;                     // 32768 f32
    float* scores   = ws + 32768;             // 65536 f32
    u16*   wT       = (u16*)(ws + 98304);     // 1M bf16 (2 MB)
    u16*   encbf    = (u16*)(ws + 622592);    // 64M bf16 (128 MB)
    float* attn     = out + 32768;

    // zero dec_proj + scores in one shot (contiguous), and the context accumulator
    hipMemsetAsync(ws, 0, 98304 * sizeof(float), stream);
    hipMemsetAsync(out, 0, 32768 * sizeof(float), stream);

    convert_enc<<<2048, 256, 0, stream>>>(enc, encbf);
    transpose_wenc<<<512, 256, 0, stream>>>(W_enc, wT);
    dec_proj_kernel<<<dim3(4, 4, 32), 256, 0, stream>>>(dec_hidden, W_dec, b_dec, dec_proj);
    score_gemm_bf<<<dim3(8, 512), 256, 0, stream>>>(encbf, wT, dec_proj, b_enc, w_att, scores);
    softmax_kernel<<<32, 256, 0, stream>>>(scores, mask, attn);
    context_bf<<<dim3(8, 32), 256, 0, stream>>>(attn, encbf, out);
}